// Round 1
// baseline (5346.378 us; speedup 1.0000x reference)
//
#include <hip/hip_runtime.h>
#include <math.h>

#define B_ 4
#define T_ 2048
#define D_ 1024
#define H_ 16
#define DK_ 64
#define EPS_ 1e-5f

// ---------------------------------------------------------------------------
// LayerNorm: one block per row (B*T rows), 256 threads, float4 per thread.
// ---------------------------------------------------------------------------
__global__ __launch_bounds__(256) void ln_kernel(const float* __restrict__ x,
                                                 const float* __restrict__ w,
                                                 const float* __restrict__ b,
                                                 float* __restrict__ h) {
  const int row = blockIdx.x;
  const float4 v = ((const float4*)(x + (size_t)row * D_))[threadIdx.x];
  float s  = v.x + v.y + v.z + v.w;
  float ss = v.x*v.x + v.y*v.y + v.z*v.z + v.w*v.w;
  #pragma unroll
  for (int o = 32; o > 0; o >>= 1) {
    s  += __shfl_down(s,  o);
    ss += __shfl_down(ss, o);
  }
  __shared__ float red[8];
  const int wid = threadIdx.x >> 6, lane = threadIdx.x & 63;
  if (lane == 0) { red[wid] = s; red[wid + 4] = ss; }
  __syncthreads();
  s  = red[0] + red[1] + red[2] + red[3];
  ss = red[4] + red[5] + red[6] + red[7];
  const float mu  = s * (1.0f / D_);
  const float var = ss * (1.0f / D_) - mu * mu;
  const float inv = rsqrtf(var + EPS_);
  const float4 wv = ((const float4*)w)[threadIdx.x];
  const float4 bv = ((const float4*)b)[threadIdx.x];
  float4 o;
  o.x = (v.x - mu) * inv * wv.x + bv.x;
  o.y = (v.y - mu) * inv * wv.y + bv.y;
  o.z = (v.z - mu) * inv * wv.z + bv.z;
  o.w = (v.w - mu) * inv * wv.w + bv.w;
  ((float4*)(h + (size_t)row * D_))[threadIdx.x] = o;
}

// ---------------------------------------------------------------------------
// fp32 SGEMM + bias: C[M,N] = A[M,K] @ B[K,N] + bias[N]
// BM=128 BN=64 BK=16, 256 threads, 8x4 micro-tile per thread.
// ---------------------------------------------------------------------------
#define BM 128
#define BN 64
#define BK 16
__global__ __launch_bounds__(256) void sgemm_bias(const float* __restrict__ A,
                                                  const float* __restrict__ Bm,
                                                  const float* __restrict__ bias,
                                                  float* __restrict__ C,
                                                  int M, int N, int K) {
  __shared__ float As[BK][BM + 4];   // transposed tile: As[k][m]
  __shared__ float Bs[BK][BN + 4];
  const int tid = threadIdx.x;
  const int m0 = blockIdx.y * BM, n0 = blockIdx.x * BN;
  const int tx = tid & 15, ty = tid >> 4;
  float c[8][4] = {};
  for (int k0 = 0; k0 < K; k0 += BK) {
    // stage A tile: 128x16 floats = 512 float4, 2 per thread, store transposed
    #pragma unroll
    for (int r = 0; r < 2; ++r) {
      const int f = tid + r * 256;
      const int row = f >> 2, cc = (f & 3) * 4;
      const float4 v = *(const float4*)(A + (size_t)(m0 + row) * K + k0 + cc);
      As[cc + 0][row] = v.x; As[cc + 1][row] = v.y;
      As[cc + 2][row] = v.z; As[cc + 3][row] = v.w;
    }
    // stage B tile: 16x64 floats = 256 float4, 1 per thread
    {
      const int row = tid >> 4, cc = (tid & 15) * 4;
      const float4 v = *(const float4*)(Bm + (size_t)(k0 + row) * N + n0 + cc);
      *(float4*)&Bs[row][cc] = v;
    }
    __syncthreads();
    #pragma unroll
    for (int k = 0; k < BK; ++k) {
      float a[8], bb[4];
      #pragma unroll
      for (int i = 0; i < 8; ++i) a[i] = As[k][ty * 8 + i];
      #pragma unroll
      for (int j = 0; j < 4; ++j) bb[j] = Bs[k][tx * 4 + j];
      #pragma unroll
      for (int i = 0; i < 8; ++i)
        #pragma unroll
        for (int j = 0; j < 4; ++j)
          c[i][j] += a[i] * bb[j];
    }
    __syncthreads();
  }
  #pragma unroll
  for (int i = 0; i < 8; ++i) {
    const int row = m0 + ty * 8 + i;
    const int col = n0 + tx * 4;
    float4 o;
    o.x = c[i][0] + bias[col + 0];
    o.y = c[i][1] + bias[col + 1];
    o.z = c[i][2] + bias[col + 2];
    o.w = c[i][3] + bias[col + 3];
    *(float4*)(C + (size_t)row * N + col) = o;
  }
}

// ---------------------------------------------------------------------------
// RoPE in place on q and k sections of qkv. One block per (b,t) row.
// qkv layout: [(b*T+t)][ sec*1024 + h*64 + d ], sec = 0:q 1:k 2:v
// ---------------------------------------------------------------------------
__global__ __launch_bounds__(256) void rope_kernel(float* __restrict__ qkv) {
  const int bt = blockIdx.x;
  const int t = bt % T_;
  float* row = qkv + (size_t)bt * (3 * D_);
  #pragma unroll
  for (int u = 0; u < 4; ++u) {
    const int p = threadIdx.x + (u & 1) * 256;   // pair index 0..511
    const int sec = u >> 1;                       // 0 = q, 1 = k
    const int hh = p >> 5, d = p & 31;
    const float inv = powf(10000.0f, -(float)d / 32.0f);
    const float f = (float)t * inv;
    float sn, cs;
    sincosf(f, &sn, &cs);
    float* base = row + sec * D_ + hh * DK_;
    const float x1 = base[d], x2 = base[d + 32];
    base[d]      = x1 * cs - x2 * sn;
    base[d + 32] = x2 * cs + x1 * sn;
  }
}

// ---------------------------------------------------------------------------
// Causal flash attention, fp32. One thread per q-row, 1-wave blocks.
// grid = (T/64, H, B). K/V tiles of 32 keys staged in LDS, broadcast reads.
// Writes attn_out in (b, t, h*64+d) layout (ready for out-proj GEMM).
// ---------------------------------------------------------------------------
#define TQ 64
#define TK 32
__global__ __launch_bounds__(64) void flash_kernel(const float* __restrict__ qkv,
                                                   float* __restrict__ out) {
  __shared__ float Ks[TK][DK_];
  __shared__ float Vs[TK][DK_];
  const int tid = threadIdx.x;
  const int bx = blockIdx.x, hh = blockIdx.y, b = blockIdx.z;
  const int qrow = bx * TQ + tid;

  const float* qp = qkv + (size_t)(b * T_ + qrow) * (3 * D_) + hh * DK_;
  float q[DK_];
  #pragma unroll
  for (int i = 0; i < 16; ++i) {
    const float4 v = *(const float4*)(qp + i * 4);
    q[i*4+0] = v.x * 0.125f; q[i*4+1] = v.y * 0.125f;
    q[i*4+2] = v.z * 0.125f; q[i*4+3] = v.w * 0.125f;
  }
  float acc[DK_] = {};
  float m = -INFINITY, l = 0.0f;

  const float* kbase = qkv + (size_t)b * T_ * (3 * D_) + D_ + hh * DK_;
  const float* vbase = kbase + D_;
  const int nt = ((bx + 1) * TQ) / TK;

  for (int kt = 0; kt < nt; ++kt) {
    const int kk = kt * TK;
    __syncthreads();
    #pragma unroll
    for (int i = 0; i < 8; ++i) {
      const int f = tid + i * 64;            // 0..511 over 2 tiles of float4
      const int r = f >> 4, cc = (f & 15) * 4;
      *(float4*)&Ks[r][cc] = *(const float4*)(kbase + (size_t)(kk + r) * (3 * D_) + cc);
      *(float4*)&Vs[r][cc] = *(const float4*)(vbase + (size_t)(kk + r) * (3 * D_) + cc);
    }
    __syncthreads();

    float s[TK];
    float tm = -INFINITY;
    #pragma unroll
    for (int j = 0; j < TK; ++j) {
      float d0 = 0.0f;
      #pragma unroll
      for (int i = 0; i < 16; ++i) {
        const float4 kv = *(const float4*)&Ks[j][i * 4];
        d0 += q[i*4+0]*kv.x + q[i*4+1]*kv.y + q[i*4+2]*kv.z + q[i*4+3]*kv.w;
      }
      s[j] = (kk + j <= qrow) ? d0 : -INFINITY;
      tm = fmaxf(tm, s[j]);
    }
    const float mn = fmaxf(m, tm);
    const float alpha = expf(m - mn);   // m=-inf on first tile -> alpha=0
    l *= alpha;
    #pragma unroll
    for (int d = 0; d < DK_; ++d) acc[d] *= alpha;
    #pragma unroll
    for (int j = 0; j < TK; ++j) {
      const float p = expf(s[j] - mn);  // masked -> exp(-inf)=0
      l += p;
      #pragma unroll
      for (int i = 0; i < 16; ++i) {
        const float4 vv = *(const float4*)&Vs[j][i * 4];
        acc[i*4+0] += p * vv.x; acc[i*4+1] += p * vv.y;
        acc[i*4+2] += p * vv.z; acc[i*4+3] += p * vv.w;
      }
    }
    m = mn;
  }

  const float invl = 1.0f / l;
  float* op = out + (size_t)(b * T_ + qrow) * D_ + hh * DK_;
  #pragma unroll
  for (int i = 0; i < 16; ++i) {
    float4 o;
    o.x = acc[i*4+0] * invl; o.y = acc[i*4+1] * invl;
    o.z = acc[i*4+2] * invl; o.w = acc[i*4+3] * invl;
    *(float4*)(op + i * 4) = o;
  }
}

// ---------------------------------------------------------------------------
// launch
// ---------------------------------------------------------------------------
extern "C" void kernel_launch(void* const* d_in, const int* in_sizes, int n_in,
                              void* d_out, int out_size, void* d_ws, size_t ws_size,
                              hipStream_t stream) {
  const float* x     = (const float*)d_in[0];
  const float* ln_w  = (const float*)d_in[1];
  const float* ln_b  = (const float*)d_in[2];
  const float* w_qkv = (const float*)d_in[3];
  const float* b_qkv = (const float*)d_in[4];
  const float* w_o   = (const float*)d_in[5];
  const float* b_o   = (const float*)d_in[6];
  float* outp = (float*)d_out;

  // workspace: h (8.4M) | qkv (25.2M) | attn_out (8.4M) floats = 167.8 MB
  float* h   = (float*)d_ws;
  float* qkv = h + (size_t)B_ * T_ * D_;
  float* att = qkv + (size_t)B_ * T_ * 3 * D_;

  const int rows = B_ * T_;   // 8192

  ln_kernel<<<rows, 256, 0, stream>>>(x, ln_w, ln_b, h);

  {
    dim3 grid(3 * D_ / BN, rows / BM);   // (48, 64)
    sgemm_bias<<<grid, 256, 0, stream>>>(h, w_qkv, b_qkv, qkv, rows, 3 * D_, D_);
  }

  rope_kernel<<<rows, 256, 0, stream>>>(qkv);

  {
    dim3 grid(T_ / TQ, H_, B_);          // (32, 16, 4)
    flash_kernel<<<grid, 64, 0, stream>>>(qkv, att);
  }

  {
    dim3 grid(D_ / BN, rows / BM);       // (16, 64)
    sgemm_bias<<<grid, 256, 0, stream>>>(att, w_o, b_o, outp, rows, D_, D_);
  }
}

// Round 4
// 447.437 us; speedup vs baseline: 11.9489x; 11.9489x over previous
//
#include <hip/hip_runtime.h>
#include <math.h>

#define B_ 4
#define T_ 2048
#define D_ 1024
#define H_ 16
#define DK_ 64
#define EPS_ 1e-5f

typedef __attribute__((ext_vector_type(4))) float f32x4;
typedef __attribute__((ext_vector_type(8))) short sv8;
typedef __attribute__((ext_vector_type(4))) short sv4;

__device__ __forceinline__ short f2bf(float f) {
  union { float f; unsigned u; } x; x.f = f;
  unsigned r = x.u + 0x7fffu + ((x.u >> 16) & 1u);
  return (short)(r >> 16);
}

// ---------------------------------------------------------------------------
// LayerNorm: one block per row, 256 threads, float4 per thread. Emits bf16.
// ---------------------------------------------------------------------------
__global__ __launch_bounds__(256) void ln_kernel(const float* __restrict__ x,
                                                 const float* __restrict__ w,
                                                 const float* __restrict__ b,
                                                 short* __restrict__ h) {
  const int row = blockIdx.x;
  const float4 v = ((const float4*)(x + (size_t)row * D_))[threadIdx.x];
  float s  = v.x + v.y + v.z + v.w;
  float ss = v.x*v.x + v.y*v.y + v.z*v.z + v.w*v.w;
  #pragma unroll
  for (int o = 32; o > 0; o >>= 1) {
    s  += __shfl_down(s,  o);
    ss += __shfl_down(ss, o);
  }
  __shared__ float red[8];
  const int wid = threadIdx.x >> 6, lane = threadIdx.x & 63;
  if (lane == 0) { red[wid] = s; red[wid + 4] = ss; }
  __syncthreads();
  s  = red[0] + red[1] + red[2] + red[3];
  ss = red[4] + red[5] + red[6] + red[7];
  const float mu  = s * (1.0f / D_);
  const float var = ss * (1.0f / D_) - mu * mu;
  const float inv = rsqrtf(var + EPS_);
  const float4 wv = ((const float4*)w)[threadIdx.x];
  const float4 bv = ((const float4*)b)[threadIdx.x];
  sv4 o;
  o[0] = f2bf((v.x - mu) * inv * wv.x + bv.x);
  o[1] = f2bf((v.y - mu) * inv * wv.y + bv.y);
  o[2] = f2bf((v.z - mu) * inv * wv.z + bv.z);
  o[3] = f2bf((v.w - mu) * inv * wv.w + bv.w);
  ((sv4*)(h + (size_t)row * D_))[threadIdx.x] = o;
}

// ---------------------------------------------------------------------------
// Transpose + fp32->bf16 convert: WT[n][k] = bf16(W[k][n]). 32x32 LDS tiles.
// ---------------------------------------------------------------------------
__global__ __launch_bounds__(256) void conv_t(const float* __restrict__ W,
                                              short* __restrict__ WT,
                                              int K, int N) {
  __shared__ float tile[32][33];
  const int k0 = blockIdx.y * 32, n0 = blockIdx.x * 32;
  const int tx = threadIdx.x & 31, ty = threadIdx.x >> 5;
  #pragma unroll
  for (int i = 0; i < 4; ++i) {
    const int k = ty * 4 + i;
    tile[k][tx] = W[(size_t)(k0 + k) * N + n0 + tx];
  }
  __syncthreads();
  #pragma unroll
  for (int i = 0; i < 4; ++i) {
    const int n = ty * 4 + i;
    WT[(size_t)(n0 + n) * K + k0 + tx] = f2bf(tile[tx][n]);
  }
}

// ---------------------------------------------------------------------------
// bf16 MFMA GEMM + bias: C[M,N] = A[M,K] @ BT[N,K]^T + bias[N], fp32 out.
// 128x128x32 tile, 256 thr = 4 waves (2x2), each wave 64x64 via 4x4 frags.
// ---------------------------------------------------------------------------
#define GBM 128
#define GBN 128
#define GBK 32
__global__ __launch_bounds__(256) void gemm_bf16(const short* __restrict__ A,
                                                 const short* __restrict__ BT,
                                                 const float* __restrict__ bias,
                                                 float* __restrict__ C,
                                                 int M, int N, int K) {
  __shared__ __align__(16) short As[GBM][GBK];
  __shared__ __align__(16) short Bs[GBN][GBK];
  const int tid = threadIdx.x;
  const int l = tid & 63, g = l >> 4, lq = l & 15;
  const int wm = (tid >> 6) >> 1, wn = (tid >> 6) & 1;
  const int m0 = blockIdx.y * GBM, n0 = blockIdx.x * GBN;

  f32x4 acc[4][4] = {};

  for (int k0 = 0; k0 < K; k0 += GBK) {
    __syncthreads();
    #pragma unroll
    for (int r = 0; r < 2; ++r) {
      const int c = tid + r * 256;          // 16B chunk id, 512 per tile
      const int row = c >> 2, co = (c & 3) * 8;
      *(int4*)&As[row][co] = *(const int4*)(A + (size_t)(m0 + row) * K + k0 + co);
      *(int4*)&Bs[row][co] = *(const int4*)(BT + (size_t)(n0 + row) * K + k0 + co);
    }
    __syncthreads();
    sv8 af[4], bf[4];
    #pragma unroll
    for (int mi = 0; mi < 4; ++mi) af[mi] = *(const sv8*)&As[64 * wm + 16 * mi + lq][8 * g];
    #pragma unroll
    for (int ni = 0; ni < 4; ++ni) bf[ni] = *(const sv8*)&Bs[64 * wn + 16 * ni + lq][8 * g];
    #pragma unroll
    for (int mi = 0; mi < 4; ++mi)
      #pragma unroll
      for (int ni = 0; ni < 4; ++ni)
        acc[mi][ni] = __builtin_amdgcn_mfma_f32_16x16x32_bf16(af[mi], bf[ni], acc[mi][ni], 0, 0, 0);
  }

  #pragma unroll
  for (int ni = 0; ni < 4; ++ni) {
    const int col = n0 + 64 * wn + 16 * ni + lq;
    const float bb = bias[col];
    #pragma unroll
    for (int mi = 0; mi < 4; ++mi) {
      const int rbase = m0 + 64 * wm + 16 * mi + 4 * g;
      #pragma unroll
      for (int r = 0; r < 4; ++r)
        C[(size_t)(rbase + r) * N + col] = acc[mi][ni][r] + bb;
    }
  }
}

// ---------------------------------------------------------------------------
// RoPE in place on q and k sections of qkv (fp32).
// ---------------------------------------------------------------------------
__global__ __launch_bounds__(256) void rope_kernel(float* __restrict__ qkv) {
  const int bt = blockIdx.x;
  const int t = bt % T_;
  float* row = qkv + (size_t)bt * (3 * D_);
  #pragma unroll
  for (int u = 0; u < 4; ++u) {
    const int p = threadIdx.x + (u & 1) * 256;
    const int sec = u >> 1;
    const int hh = p >> 5, d = p & 31;
    const float inv = powf(10000.0f, -(float)d / 32.0f);
    const float f = (float)t * inv;
    float sn, cs;
    sincosf(f, &sn, &cs);
    float* base = row + sec * D_ + hh * DK_;
    const float x1 = base[d], x2 = base[d + 32];
    base[d]      = x1 * cs - x2 * sn;
    base[d + 32] = x2 * cs + x1 * sn;
  }
}

// ---------------------------------------------------------------------------
// MFMA flash attention, bf16 inputs / fp32 softmax+accum. Emits bf16 att.
// Block = 4 waves; each wave owns 16 q rows; KV tiles of 64 keys.
// Swapped QK^T (S^T = K·Q^T) -> lane holds 16 scores of ONE q-row.
// ---------------------------------------------------------------------------
__global__ __launch_bounds__(256) void flash_mfma(const float* __restrict__ qkv,
                                                  short* __restrict__ out) {
  __shared__ __align__(16) short Ks[64][72];
  __shared__ __align__(16) short Vt[64][72];
  __shared__ __align__(16) short Ps[4][16][72];

  const int tid = threadIdx.x;
  const int w = tid >> 6, l = tid & 63, g = l >> 4, lq = l & 15;
  const int bx = blockIdx.x, hh = blockIdx.y, b = blockIdx.z;
  const int q0 = bx * 64;

  const int qrow = q0 + 16 * w + lq;
  const float* qp = qkv + (size_t)(b * T_ + qrow) * (3 * D_) + hh * DK_;
  sv8 qf[2];
  #pragma unroll
  for (int s = 0; s < 2; ++s) {
    const int d0 = 32 * s + 8 * g;
    const float4 v0 = *(const float4*)(qp + d0);
    const float4 v1 = *(const float4*)(qp + d0 + 4);
    sv8 f;
    f[0] = f2bf(v0.x * 0.125f); f[1] = f2bf(v0.y * 0.125f);
    f[2] = f2bf(v0.z * 0.125f); f[3] = f2bf(v0.w * 0.125f);
    f[4] = f2bf(v1.x * 0.125f); f[5] = f2bf(v1.y * 0.125f);
    f[6] = f2bf(v1.z * 0.125f); f[7] = f2bf(v1.w * 0.125f);
    qf[s] = f;
  }

  f32x4 o[4] = {{0,0,0,0},{0,0,0,0},{0,0,0,0},{0,0,0,0}};
  float m_run = -INFINITY, l_run = 0.0f;

  const float* kbase = qkv + (size_t)b * T_ * (3 * D_) + D_ + hh * DK_;
  const float* vbase = kbase + D_;

  const int niter = bx + 1;
  const int skey = tid >> 2, sc = tid & 3;

  for (int it = 0; it < niter; ++it) {
    const int kv0 = it * 64;
    __syncthreads();
    {
      const float* kp = kbase + (size_t)(kv0 + skey) * (3 * D_) + sc * 16;
      #pragma unroll
      for (int i = 0; i < 4; ++i) {
        const float4 v = *(const float4*)(kp + 4 * i);
        sv4 s4; s4[0] = f2bf(v.x); s4[1] = f2bf(v.y); s4[2] = f2bf(v.z); s4[3] = f2bf(v.w);
        *(sv4*)&Ks[skey][sc * 16 + 4 * i] = s4;
      }
    }
    {
      const float* vp = vbase + (size_t)(kv0 + skey) * (3 * D_) + sc * 4;
      #pragma unroll
      for (int i = 0; i < 4; ++i) {
        const float4 v = *(const float4*)(vp + 16 * i);
        const int d = sc * 4 + 16 * i;
        Vt[d + 0][skey] = f2bf(v.x);
        Vt[d + 1][skey] = f2bf(v.y);
        Vt[d + 2][skey] = f2bf(v.z);
        Vt[d + 3][skey] = f2bf(v.w);
      }
    }
    __syncthreads();

    float sv[4][4];
    #pragma unroll
    for (int kt = 0; kt < 4; ++kt) {
      f32x4 acc = {0, 0, 0, 0};
      #pragma unroll
      for (int s = 0; s < 2; ++s) {
        const sv8 kf = *(const sv8*)&Ks[kt * 16 + lq][32 * s + 8 * g];
        acc = __builtin_amdgcn_mfma_f32_16x16x32_bf16(kf, qf[s], acc, 0, 0, 0);
      }
      sv[kt][0] = acc[0]; sv[kt][1] = acc[1]; sv[kt][2] = acc[2]; sv[kt][3] = acc[3];
    }

    if (it == niter - 1) {
      #pragma unroll
      for (int kt = 0; kt < 4; ++kt)
        #pragma unroll
        for (int r = 0; r < 4; ++r) {
          const int key_abs = kv0 + kt * 16 + 4 * g + r;
          if (key_abs > qrow) sv[kt][r] = -INFINITY;
        }
    }

    float tm = -INFINITY;
    #pragma unroll
    for (int kt = 0; kt < 4; ++kt)
      #pragma unroll
      for (int r = 0; r < 4; ++r) tm = fmaxf(tm, sv[kt][r]);
    tm = fmaxf(tm, __shfl_xor(tm, 16));
    tm = fmaxf(tm, __shfl_xor(tm, 32));
    const float mn = fmaxf(m_run, tm);
    const float alpha = __expf(m_run - mn);
    float psum = 0.0f;
    #pragma unroll
    for (int kt = 0; kt < 4; ++kt)
      #pragma unroll
      for (int r = 0; r < 4; ++r) {
        const float p = __expf(sv[kt][r] - mn);
        sv[kt][r] = p;
        psum += p;
      }
    psum += __shfl_xor(psum, 16);
    psum += __shfl_xor(psum, 32);
    l_run = l_run * alpha + psum;
    m_run = mn;

    #pragma unroll
    for (int r = 0; r < 4; ++r) {
      const float ar = __shfl(alpha, 4 * g + r);
      o[0][r] *= ar; o[1][r] *= ar; o[2][r] *= ar; o[3][r] *= ar;
    }

    #pragma unroll
    for (int kt = 0; kt < 4; ++kt) {
      sv4 p4;
      p4[0] = f2bf(sv[kt][0]); p4[1] = f2bf(sv[kt][1]);
      p4[2] = f2bf(sv[kt][2]); p4[3] = f2bf(sv[kt][3]);
      *(sv4*)&Ps[w][lq][kt * 16 + 4 * g] = p4;
    }

    #pragma unroll
    for (int s = 0; s < 2; ++s) {
      const sv8 pa = *(const sv8*)&Ps[w][lq][32 * s + 8 * g];
      #pragma unroll
      for (int dt = 0; dt < 4; ++dt) {
        const sv8 vb = *(const sv8*)&Vt[dt * 16 + lq][32 * s + 8 * g];
        o[dt] = __builtin_amdgcn_mfma_f32_16x16x32_bf16(pa, vb, o[dt], 0, 0, 0);
      }
    }
  }

  #pragma unroll
  for (int r = 0; r < 4; ++r) {
    const float li = __shfl(l_run, 4 * g + r);
    const float inv = 1.0f / li;
    const int qr = q0 + 16 * w + 4 * g + r;
    short* op = out + (size_t)(b * T_ + qr) * D_ + hh * DK_;
    #pragma unroll
    for (int dt = 0; dt < 4; ++dt)
      op[dt * 16 + lq] = f2bf(o[dt][r] * inv);
  }
}

// ---------------------------------------------------------------------------
// launch
// ---------------------------------------------------------------------------
extern "C" void kernel_launch(void* const* d_in, const int* in_sizes, int n_in,
                              void* d_out, int out_size, void* d_ws, size_t ws_size,
                              hipStream_t stream) {
  const float* x     = (const float*)d_in[0];
  const float* ln_w  = (const float*)d_in[1];
  const float* ln_b  = (const float*)d_in[2];
  const float* w_qkv = (const float*)d_in[3];
  const float* b_qkv = (const float*)d_in[4];
  const float* w_o   = (const float*)d_in[5];
  const float* b_o   = (const float*)d_in[6];
  float* outp = (float*)d_out;

  const int rows = B_ * T_;          // 8192
  const size_t nHD = (size_t)rows * D_;

  // ws layout (bytes): h bf16 16.8M | qkv f32 100.7M | att bf16 16.8M |
  //                    wqkvT bf16 6.3M | woT bf16 2.1M   -> ~143 MB
  short* h      = (short*)d_ws;
  float* qkv    = (float*)(h + nHD);
  short* att    = (short*)(qkv + (size_t)rows * 3 * D_);
  short* wqkvT  = att + nHD;
  short* woT    = wqkvT + (size_t)D_ * 3 * D_;

  conv_t<<<dim3(3 * D_ / 32, D_ / 32), 256, 0, stream>>>(w_qkv, wqkvT, D_, 3 * D_);
  conv_t<<<dim3(D_ / 32, D_ / 32), 256, 0, stream>>>(w_o, woT, D_, D_);

  ln_kernel<<<rows, 256, 0, stream>>>(x, ln_w, ln_b, h);

  {
    dim3 grid(3 * D_ / GBN, rows / GBM);   // (24, 64)
    gemm_bf16<<<grid, 256, 0, stream>>>(h, wqkvT, b_qkv, qkv, rows, 3 * D_, D_);
  }

  rope_kernel<<<rows, 256, 0, stream>>>(qkv);

  {
    dim3 grid(T_ / 64, H_, B_);            // (32, 16, 4)
    flash_mfma<<<grid, 256, 0, stream>>>(qkv, att);
  }

  {
    dim3 grid(D_ / GBN, rows / GBM);       // (8, 64)
    gemm_bf16<<<grid, 256, 0, stream>>>(att, woT, b_o, outp, rows, D_, D_);
  }
}

// Round 5
// 374.089 us; speedup vs baseline: 14.2917x; 1.1961x over previous
//
#include <hip/hip_runtime.h>
#include <math.h>

#define B_ 4
#define T_ 2048
#define D_ 1024
#define H_ 16
#define DK_ 64
#define EPS_ 1e-5f

typedef __attribute__((ext_vector_type(4))) float f32x4;
typedef __attribute__((ext_vector_type(8))) short sv8;
typedef __attribute__((ext_vector_type(4))) short sv4;

__device__ __forceinline__ short f2bf(float f) {
  union { float f; unsigned u; } x; x.f = f;
  unsigned r = x.u + 0x7fffu + ((x.u >> 16) & 1u);
  return (short)(r >> 16);
}

// ---------------------------------------------------------------------------
// RoPE cos/sin table: cs[t][f] = (cos(t*invf), sin(t*invf)), invf=10000^{-f/32}
// ---------------------------------------------------------------------------
__global__ __launch_bounds__(256) void rope_tab(float2* __restrict__ cs) {
  const int i = blockIdx.x * 256 + threadIdx.x;   // < 2048*32
  const int t = i >> 5, f = i & 31;
  const float inv = powf(10000.0f, -(float)f / 32.0f);
  float sn, cn;
  sincosf((float)t * inv, &sn, &cn);
  cs[i] = make_float2(cn, sn);
}

// ---------------------------------------------------------------------------
// LayerNorm: one block per row, 256 threads, float4 per thread. Emits bf16.
// ---------------------------------------------------------------------------
__global__ __launch_bounds__(256) void ln_kernel(const float* __restrict__ x,
                                                 const float* __restrict__ w,
                                                 const float* __restrict__ b,
                                                 short* __restrict__ h) {
  const int row = blockIdx.x;
  const float4 v = ((const float4*)(x + (size_t)row * D_))[threadIdx.x];
  float s  = v.x + v.y + v.z + v.w;
  float ss = v.x*v.x + v.y*v.y + v.z*v.z + v.w*v.w;
  #pragma unroll
  for (int o = 32; o > 0; o >>= 1) {
    s  += __shfl_down(s,  o);
    ss += __shfl_down(ss, o);
  }
  __shared__ float red[8];
  const int wid = threadIdx.x >> 6, lane = threadIdx.x & 63;
  if (lane == 0) { red[wid] = s; red[wid + 4] = ss; }
  __syncthreads();
  s  = red[0] + red[1] + red[2] + red[3];
  ss = red[4] + red[5] + red[6] + red[7];
  const float mu  = s * (1.0f / D_);
  const float var = ss * (1.0f / D_) - mu * mu;
  const float inv = rsqrtf(var + EPS_);
  const float4 wv = ((const float4*)w)[threadIdx.x];
  const float4 bv = ((const float4*)b)[threadIdx.x];
  sv4 o;
  o[0] = f2bf((v.x - mu) * inv * wv.x + bv.x);
  o[1] = f2bf((v.y - mu) * inv * wv.y + bv.y);
  o[2] = f2bf((v.z - mu) * inv * wv.z + bv.z);
  o[3] = f2bf((v.w - mu) * inv * wv.w + bv.w);
  ((sv4*)(h + (size_t)row * D_))[threadIdx.x] = o;
}

// ---------------------------------------------------------------------------
// Transpose + fp32->bf16 convert: WT[n][k] = bf16(W[k][n]). 32x32 LDS tiles.
// ---------------------------------------------------------------------------
__global__ __launch_bounds__(256) void conv_t(const float* __restrict__ W,
                                              short* __restrict__ WT,
                                              int K, int N) {
  __shared__ float tile[32][33];
  const int k0 = blockIdx.y * 32, n0 = blockIdx.x * 32;
  const int tx = threadIdx.x & 31, ty = threadIdx.x >> 5;
  #pragma unroll
  for (int i = 0; i < 4; ++i) {
    const int k = ty * 4 + i;
    tile[k][tx] = W[(size_t)(k0 + k) * N + n0 + tx];
  }
  __syncthreads();
  #pragma unroll
  for (int i = 0; i < 4; ++i) {
    const int n = ty * 4 + i;
    WT[(size_t)(n0 + n) * K + k0 + tx] = f2bf(tile[tx][n]);
  }
}

#define GBM 128
#define GBN 128
#define GBK 32

// ---------------------------------------------------------------------------
// QKV GEMM + bias + fused RoPE. A[8192,1024] bf16, BT[3072,1024] bf16.
// Epilogue: sec0 -> q (rope, *0.125) bf16 [bt][1024]; sec1 -> k (rope) same;
// sec2 -> v written TRANSPOSED vt[b][h][d][t] bf16.
// ---------------------------------------------------------------------------
__global__ __launch_bounds__(256) void gemm_qkv_rope(const short* __restrict__ A,
                                                     const short* __restrict__ BT,
                                                     const float* __restrict__ bias,
                                                     const float2* __restrict__ cs,
                                                     short* __restrict__ qb,
                                                     short* __restrict__ kb,
                                                     short* __restrict__ vt) {
  __shared__ __align__(16) short As[GBM][GBK];
  __shared__ __align__(16) short Bs[GBN][GBK];
  const int tid = threadIdx.x;
  const int l = tid & 63, g = l >> 4, lq = l & 15;
  const int wm = (tid >> 6) >> 1, wn = (tid >> 6) & 1;
  const int m0 = blockIdx.y * GBM, n0 = blockIdx.x * GBN;
  const int M = B_ * T_, N = 3 * D_, K = D_;
  (void)M;

  f32x4 acc[4][4] = {};

  for (int k0 = 0; k0 < K; k0 += GBK) {
    __syncthreads();
    #pragma unroll
    for (int r = 0; r < 2; ++r) {
      const int c = tid + r * 256;
      const int row = c >> 2, co = (c & 3) * 8;
      *(int4*)&As[row][co] = *(const int4*)(A + (size_t)(m0 + row) * K + k0 + co);
      *(int4*)&Bs[row][co] = *(const int4*)(BT + (size_t)(n0 + row) * K + k0 + co);
    }
    __syncthreads();
    sv8 af[4], bf[4];
    #pragma unroll
    for (int mi = 0; mi < 4; ++mi) af[mi] = *(const sv8*)&As[64 * wm + 16 * mi + lq][8 * g];
    #pragma unroll
    for (int ni = 0; ni < 4; ++ni) bf[ni] = *(const sv8*)&Bs[64 * wn + 16 * ni + lq][8 * g];
    #pragma unroll
    for (int mi = 0; mi < 4; ++mi)
      #pragma unroll
      for (int ni = 0; ni < 4; ++ni)
        acc[mi][ni] = __builtin_amdgcn_mfma_f32_16x16x32_bf16(af[mi], bf[ni], acc[mi][ni], 0, 0, 0);
  }

  const int sec = n0 >> 10;          // uniform per block (1024 % 128 == 0)
  if (sec < 2) {
    short* dst = (sec == 0) ? qb : kb;
    const float qs = (sec == 0) ? 0.125f : 1.0f;
    #pragma unroll
    for (int nA = 0; nA < 2; ++nA) {
      const int colA = n0 + 64 * wn + 16 * nA + lq;
      const float bA = bias[colA], bB = bias[colA + 32];
      const int clA = colA & 1023;
      const int f = 16 * nA + lq;           // 0..31
      #pragma unroll
      for (int mi = 0; mi < 4; ++mi) {
        const int rbase = m0 + 64 * wm + 16 * mi + 4 * g;
        #pragma unroll
        for (int r = 0; r < 4; ++r) {
          const int row = rbase + r, t = row & (T_ - 1);
          const float2 c_s = cs[t * 32 + f];
          const float x1 = acc[mi][nA][r] + bA;
          const float x2 = acc[mi][nA + 2][r] + bB;
          dst[(size_t)row * D_ + clA]      = f2bf((x1 * c_s.x - x2 * c_s.y) * qs);
          dst[(size_t)row * D_ + clA + 32] = f2bf((x2 * c_s.x + x1 * c_s.y) * qs);
        }
      }
    }
  } else {
    #pragma unroll
    for (int ni = 0; ni < 4; ++ni) {
      const int col = n0 + 64 * wn + 16 * ni + lq;
      const float bb = bias[col];
      const int cl = col & 1023;
      const int hh = cl >> 6, d = cl & 63;
      #pragma unroll
      for (int mi = 0; mi < 4; ++mi) {
        const int rbase = m0 + 64 * wm + 16 * mi + 4 * g;
        #pragma unroll
        for (int r = 0; r < 4; ++r) {
          const int row = rbase + r;
          const int bI = row >> 11, t = row & (T_ - 1);
          vt[((size_t)(bI * H_ + hh) * DK_ + d) * T_ + t] = f2bf(acc[mi][ni][r] + bb);
        }
      }
    }
  }
}

// ---------------------------------------------------------------------------
// Plain bf16 MFMA GEMM + bias, fp32 C out (out-projection).
// ---------------------------------------------------------------------------
__global__ __launch_bounds__(256) void gemm_bf16(const short* __restrict__ A,
                                                 const short* __restrict__ BT,
                                                 const float* __restrict__ bias,
                                                 float* __restrict__ C,
                                                 int M, int N, int K) {
  __shared__ __align__(16) short As[GBM][GBK];
  __shared__ __align__(16) short Bs[GBN][GBK];
  const int tid = threadIdx.x;
  const int l = tid & 63, g = l >> 4, lq = l & 15;
  const int wm = (tid >> 6) >> 1, wn = (tid >> 6) & 1;
  const int m0 = blockIdx.y * GBM, n0 = blockIdx.x * GBN;

  f32x4 acc[4][4] = {};

  for (int k0 = 0; k0 < K; k0 += GBK) {
    __syncthreads();
    #pragma unroll
    for (int r = 0; r < 2; ++r) {
      const int c = tid + r * 256;
      const int row = c >> 2, co = (c & 3) * 8;
      *(int4*)&As[row][co] = *(const int4*)(A + (size_t)(m0 + row) * K + k0 + co);
      *(int4*)&Bs[row][co] = *(const int4*)(BT + (size_t)(n0 + row) * K + k0 + co);
    }
    __syncthreads();
    sv8 af[4], bf[4];
    #pragma unroll
    for (int mi = 0; mi < 4; ++mi) af[mi] = *(const sv8*)&As[64 * wm + 16 * mi + lq][8 * g];
    #pragma unroll
    for (int ni = 0; ni < 4; ++ni) bf[ni] = *(const sv8*)&Bs[64 * wn + 16 * ni + lq][8 * g];
    #pragma unroll
    for (int mi = 0; mi < 4; ++mi)
      #pragma unroll
      for (int ni = 0; ni < 4; ++ni)
        acc[mi][ni] = __builtin_amdgcn_mfma_f32_16x16x32_bf16(af[mi], bf[ni], acc[mi][ni], 0, 0, 0);
  }

  #pragma unroll
  for (int ni = 0; ni < 4; ++ni) {
    const int col = n0 + 64 * wn + 16 * ni + lq;
    const float bb = bias[col];
    #pragma unroll
    for (int mi = 0; mi < 4; ++mi) {
      const int rbase = m0 + 64 * wm + 16 * mi + 4 * g;
      #pragma unroll
      for (int r = 0; r < 4; ++r)
        C[(size_t)(rbase + r) * N + col] = acc[mi][ni][r] + bb;
    }
  }
}

// ---------------------------------------------------------------------------
// MFMA flash attention v2: bf16 q/k/vt inputs, register-prefetched staging.
// Block = 4 waves; each wave owns 16 q rows; KV tiles of 64 keys.
// Swapped QK^T (S^T = K·Q^T) -> lane holds 16 scores of ONE q-row.
// ---------------------------------------------------------------------------
__global__ __launch_bounds__(256) void flash_mfma(const short* __restrict__ qb,
                                                  const short* __restrict__ kb,
                                                  const short* __restrict__ vt,
                                                  short* __restrict__ out) {
  __shared__ __align__(16) short Ks[64][72];
  __shared__ __align__(16) short Vt[64][72];
  __shared__ __align__(16) short Ps[4][16][72];

  const int tid = threadIdx.x;
  const int w = tid >> 6, l = tid & 63, g = l >> 4, lq = l & 15;
  const int bx = blockIdx.x, hh = blockIdx.y, b = blockIdx.z;
  const int q0 = bx * 64;

  // Q fragments (pre-scaled by 1/8 in the GEMM epilogue)
  const int qrow = q0 + 16 * w + lq;
  const short* qp = qb + (size_t)(b * T_ + qrow) * D_ + hh * DK_;
  sv8 qf[2];
  qf[0] = *(const sv8*)(qp + 8 * g);
  qf[1] = *(const sv8*)(qp + 32 + 8 * g);

  f32x4 o[4] = {{0,0,0,0},{0,0,0,0},{0,0,0,0},{0,0,0,0}};
  float m_run = -INFINITY, l_run = 0.0f;

  const short* kbB = kb + (size_t)(b * T_) * D_ + hh * DK_;
  const short* vtB = vt + (size_t)(b * H_ + hh) * DK_ * T_;

  const int niter = bx + 1;
  // staging chunks: c = tid -> (key, j), c = tid+256 -> (key+32, j)
  const int skey = tid >> 3, sj = tid & 7;

  int4 kr0, kr1, vr0, vr1;
  {
    kr0 = *(const int4*)(kbB + (size_t)(skey)      * D_ + sj * 8);
    kr1 = *(const int4*)(kbB + (size_t)(skey + 32) * D_ + sj * 8);
    vr0 = *(const int4*)(vtB + (size_t)(skey)      * T_ + sj * 8);
    vr1 = *(const int4*)(vtB + (size_t)(skey + 32) * T_ + sj * 8);
  }

  for (int it = 0; it < niter; ++it) {
    const int kv0 = it * 64;
    __syncthreads();
    *(int4*)&Ks[skey][sj * 8]      = kr0;
    *(int4*)&Ks[skey + 32][sj * 8] = kr1;
    *(int4*)&Vt[skey][sj * 8]      = vr0;
    *(int4*)&Vt[skey + 32][sj * 8] = vr1;
    __syncthreads();

    if (it + 1 < niter) {
      const int nk = kv0 + 64;
      kr0 = *(const int4*)(kbB + (size_t)(nk + skey)      * D_ + sj * 8);
      kr1 = *(const int4*)(kbB + (size_t)(nk + skey + 32) * D_ + sj * 8);
      vr0 = *(const int4*)(vtB + (size_t)(skey)      * T_ + nk + sj * 8);
      vr1 = *(const int4*)(vtB + (size_t)(skey + 32) * T_ + nk + sj * 8);
    }

    // --- QK^T (swapped): lane holds q=lq, keys kt*16+4g+r ---
    float sv[4][4];
    #pragma unroll
    for (int kt = 0; kt < 4; ++kt) {
      f32x4 acc = {0, 0, 0, 0};
      #pragma unroll
      for (int s = 0; s < 2; ++s) {
        const sv8 kf = *(const sv8*)&Ks[kt * 16 + lq][32 * s + 8 * g];
        acc = __builtin_amdgcn_mfma_f32_16x16x32_bf16(kf, qf[s], acc, 0, 0, 0);
      }
      sv[kt][0] = acc[0]; sv[kt][1] = acc[1]; sv[kt][2] = acc[2]; sv[kt][3] = acc[3];
    }

    if (it == niter - 1) {   // diagonal tile: causal mask
      #pragma unroll
      for (int kt = 0; kt < 4; ++kt)
        #pragma unroll
        for (int r = 0; r < 4; ++r) {
          const int key_abs = kv0 + kt * 16 + 4 * g + r;
          if (key_abs > qrow) sv[kt][r] = -INFINITY;
        }
    }

    // --- online softmax (per q = lq) ---
    float tm = -INFINITY;
    #pragma unroll
    for (int kt = 0; kt < 4; ++kt)
      #pragma unroll
      for (int r = 0; r < 4; ++r) tm = fmaxf(tm, sv[kt][r]);
    tm = fmaxf(tm, __shfl_xor(tm, 16));
    tm = fmaxf(tm, __shfl_xor(tm, 32));
    const float mn = fmaxf(m_run, tm);
    const float alpha = __expf(m_run - mn);
    float psum = 0.0f;
    #pragma unroll
    for (int kt = 0; kt < 4; ++kt)
      #pragma unroll
      for (int r = 0; r < 4; ++r) {
        const float p = __expf(sv[kt][r] - mn);
        sv[kt][r] = p;
        psum += p;
      }
    psum += __shfl_xor(psum, 16);
    psum += __shfl_xor(psum, 32);
    l_run = l_run * alpha + psum;
    m_run = mn;

    #pragma unroll
    for (int r = 0; r < 4; ++r) {
      const float ar = __shfl(alpha, 4 * g + r);
      o[0][r] *= ar; o[1][r] *= ar; o[2][r] *= ar; o[3][r] *= ar;
    }

    // --- P (bf16) to per-wave LDS ---
    #pragma unroll
    for (int kt = 0; kt < 4; ++kt) {
      sv4 p4;
      p4[0] = f2bf(sv[kt][0]); p4[1] = f2bf(sv[kt][1]);
      p4[2] = f2bf(sv[kt][2]); p4[3] = f2bf(sv[kt][3]);
      *(sv4*)&Ps[w][lq][kt * 16 + 4 * g] = p4;
    }

    // --- PV ---
    #pragma unroll
    for (int s = 0; s < 2; ++s) {
      const sv8 pa = *(const sv8*)&Ps[w][lq][32 * s + 8 * g];
      #pragma unroll
      for (int dt = 0; dt < 4; ++dt) {
        const sv8 vb = *(const sv8*)&Vt[dt * 16 + lq][32 * s + 8 * g];
        o[dt] = __builtin_amdgcn_mfma_f32_16x16x32_bf16(pa, vb, o[dt], 0, 0, 0);
      }
    }
  }

  // --- epilogue: divide by l (per O-row q = 4g+r), write bf16 ---
  #pragma unroll
  for (int r = 0; r < 4; ++r) {
    const float li = __shfl(l_run, 4 * g + r);
    const float inv = 1.0f / li;
    const int qr = q0 + 16 * w + 4 * g + r;
    short* op = out + (size_t)(b * T_ + qr) * D_ + hh * DK_;
    #pragma unroll
    for (int dt = 0; dt < 4; ++dt)
      op[dt * 16 + lq] = f2bf(o[dt][r] * inv);
  }
}

// ---------------------------------------------------------------------------
// launch
// ---------------------------------------------------------------------------
extern "C" void kernel_launch(void* const* d_in, const int* in_sizes, int n_in,
                              void* d_out, int out_size, void* d_ws, size_t ws_size,
                              hipStream_t stream) {
  const float* x     = (const float*)d_in[0];
  const float* ln_w  = (const float*)d_in[1];
  const float* ln_b  = (const float*)d_in[2];
  const float* w_qkv = (const float*)d_in[3];
  const float* b_qkv = (const float*)d_in[4];
  const float* w_o   = (const float*)d_in[5];
  const float* b_o   = (const float*)d_in[6];
  float* outp = (float*)d_out;

  const int rows = B_ * T_;          // 8192
  const size_t nHD = (size_t)rows * D_;   // 8.4M elems

  // ws layout (shorts unless noted): h | qb | kb | vt | att | wqkvT | woT | csT(float2)
  short* h      = (short*)d_ws;
  short* qb     = h + nHD;
  short* kb     = qb + nHD;
  short* vt     = kb + nHD;
  short* att    = vt + nHD;
  short* wqkvT  = att + nHD;
  short* woT    = wqkvT + (size_t)D_ * 3 * D_;
  float2* csT   = (float2*)(woT + (size_t)D_ * D_);

  rope_tab<<<T_ * 32 / 256, 256, 0, stream>>>(csT);
  conv_t<<<dim3(3 * D_ / 32, D_ / 32), 256, 0, stream>>>(w_qkv, wqkvT, D_, 3 * D_);
  conv_t<<<dim3(D_ / 32, D_ / 32), 256, 0, stream>>>(w_o, woT, D_, D_);

  ln_kernel<<<rows, 256, 0, stream>>>(x, ln_w, ln_b, h);

  {
    dim3 grid(3 * D_ / GBN, rows / GBM);   // (24, 64)
    gemm_qkv_rope<<<grid, 256, 0, stream>>>(h, wqkvT, b_qkv, csT, qb, kb, vt);
  }

  {
    dim3 grid(T_ / 64, H_, B_);            // (32, 16, 4)
    flash_mfma<<<grid, 256, 0, stream>>>(qb, kb, vt, att);
  }

  {
    dim3 grid(D_ / GBN, rows / GBM);       // (8, 64)
    gemm_bf16<<<grid, 256, 0, stream>>>(att, woT, b_o, outp, rows, D_, D_);
  }
}

// Round 8
// 305.291 us; speedup vs baseline: 17.5124x; 1.2254x over previous
//
#include <hip/hip_runtime.h>
#include <math.h>

#define B_ 4
#define T_ 2048
#define D_ 1024
#define H_ 16
#define DK_ 64
#define EPS_ 1e-5f
#define LOG2E 1.44269504f

typedef __attribute__((ext_vector_type(4))) float f32x4;
typedef __attribute__((ext_vector_type(8))) short sv8;
typedef __attribute__((ext_vector_type(4))) short sv4;

__device__ __forceinline__ short f2bf(float f) {
  union { float f; unsigned u; } x; x.f = f;
  unsigned r = x.u + 0x7fffu + ((x.u >> 16) & 1u);
  return (short)(r >> 16);
}

__device__ __forceinline__ void gload16(const void* g, void* l) {
  __builtin_amdgcn_global_load_lds((const __attribute__((address_space(1))) void*)g,
                                   (__attribute__((address_space(3))) void*)l, 16, 0, 0);
}

// ---------------------------------------------------------------------------
// RoPE cos/sin table: cs[t][f] = (cos(t*invf), sin(t*invf))
// ---------------------------------------------------------------------------
__global__ __launch_bounds__(256) void rope_tab(float2* __restrict__ cs) {
  const int i = blockIdx.x * 256 + threadIdx.x;   // < 2048*32
  const int t = i >> 5, f = i & 31;
  const float inv = powf(10000.0f, -(float)f / 32.0f);
  float sn, cn;
  sincosf((float)t * inv, &sn, &cn);
  cs[i] = make_float2(cn, sn);
}

// ---------------------------------------------------------------------------
// LayerNorm: one block per row, float4 per thread. Emits bf16.
// ---------------------------------------------------------------------------
__global__ __launch_bounds__(256) void ln_kernel(const float* __restrict__ x,
                                                 const float* __restrict__ w,
                                                 const float* __restrict__ b,
                                                 short* __restrict__ h) {
  const int row = blockIdx.x;
  const float4 v = ((const float4*)(x + (size_t)row * D_))[threadIdx.x];
  float s  = v.x + v.y + v.z + v.w;
  float ss = v.x*v.x + v.y*v.y + v.z*v.z + v.w*v.w;
  #pragma unroll
  for (int o = 32; o > 0; o >>= 1) {
    s  += __shfl_down(s,  o);
    ss += __shfl_down(ss, o);
  }
  __shared__ float red[8];
  const int wid = threadIdx.x >> 6, lane = threadIdx.x & 63;
  if (lane == 0) { red[wid] = s; red[wid + 4] = ss; }
  __syncthreads();
  s  = red[0] + red[1] + red[2] + red[3];
  ss = red[4] + red[5] + red[6] + red[7];
  const float mu  = s * (1.0f / D_);
  const float var = ss * (1.0f / D_) - mu * mu;
  const float inv = rsqrtf(var + EPS_);
  const float4 wv = ((const float4*)w)[threadIdx.x];
  const float4 bv = ((const float4*)b)[threadIdx.x];
  sv4 o;
  o[0] = f2bf((v.x - mu) * inv * wv.x + bv.x);
  o[1] = f2bf((v.y - mu) * inv * wv.y + bv.y);
  o[2] = f2bf((v.z - mu) * inv * wv.z + bv.z);
  o[3] = f2bf((v.w - mu) * inv * wv.w + bv.w);
  ((sv4*)(h + (size_t)row * D_))[threadIdx.x] = o;
}

// ---------------------------------------------------------------------------
// Transpose + fp32->bf16: WT[n][k] = bf16(W[k][n]).
// ---------------------------------------------------------------------------
__global__ __launch_bounds__(256) void conv_t(const float* __restrict__ W,
                                              short* __restrict__ WT,
                                              int K, int N) {
  __shared__ float tile[32][33];
  const int k0 = blockIdx.y * 32, n0 = blockIdx.x * 32;
  const int tx = threadIdx.x & 31, ty = threadIdx.x >> 5;
  #pragma unroll
  for (int i = 0; i < 4; ++i) {
    const int k = ty * 4 + i;
    tile[k][tx] = W[(size_t)(k0 + k) * N + n0 + tx];
  }
  __syncthreads();
  #pragma unroll
  for (int i = 0; i < 4; ++i) {
    const int n = ty * 4 + i;
    WT[(size_t)(n0 + n) * K + k0 + tx] = f2bf(tile[tx][n]);
  }
}

#define GBM 128
#define GBN 128
#define GBK 32

// stage one 128x32 A-tile + 128x32 B-tile via global_load_lds (LDS-linear)
__device__ __forceinline__ void gstage(const short* __restrict__ A,
                                       const short* __restrict__ BT,
                                       short* AsB, short* BsB,
                                       int tid, size_t aoff, size_t boff) {
  #pragma unroll
  for (int rr = 0; rr < 2; ++rr) {
    const int c = tid + rr * 256;
    const int row = c >> 2, co = (c & 3) * 8;
    gload16(A + aoff + (size_t)row * D_ + co, AsB + c * 8);
    gload16(BT + boff + (size_t)row * D_ + co, BsB + c * 8);
  }
}

// ---------------------------------------------------------------------------
// QKV GEMM + bias + fused RoPE (async dbuf staging, m97 pattern).
// q scaled 0.125*log2e (flash softmax in exp2 domain); v written transposed.
// ---------------------------------------------------------------------------
__global__ __launch_bounds__(256) void gemm_qkv_rope(const short* __restrict__ A,
                                                     const short* __restrict__ BT,
                                                     const float* __restrict__ bias,
                                                     const float2* __restrict__ cs,
                                                     short* __restrict__ qb,
                                                     short* __restrict__ kb,
                                                     short* __restrict__ vt) {
  __shared__ __align__(16) short As[2][GBM][GBK];
  __shared__ __align__(16) short Bs[2][GBN][GBK];
  const int tid = threadIdx.x;
  const int l = tid & 63, g = l >> 4, lq = l & 15;
  const int wm = (tid >> 6) >> 1, wn = (tid >> 6) & 1;
  const int m0 = blockIdx.y * GBM, n0 = blockIdx.x * GBN;

  f32x4 acc[4][4] = {};

  gstage(A, BT, &As[0][0][0], &Bs[0][0][0], tid, (size_t)m0 * D_, (size_t)n0 * D_);
  int cur = 0;
  for (int k0 = 0; k0 < D_; k0 += GBK) {
    __syncthreads();
    if (k0 + GBK < D_)
      gstage(A, BT, &As[cur ^ 1][0][0], &Bs[cur ^ 1][0][0], tid,
             (size_t)m0 * D_ + k0 + GBK, (size_t)n0 * D_ + k0 + GBK);
    sv8 af[4], bf[4];
    #pragma unroll
    for (int mi = 0; mi < 4; ++mi) af[mi] = *(const sv8*)&As[cur][64 * wm + 16 * mi + lq][8 * g];
    #pragma unroll
    for (int ni = 0; ni < 4; ++ni) bf[ni] = *(const sv8*)&Bs[cur][64 * wn + 16 * ni + lq][8 * g];
    #pragma unroll
    for (int mi = 0; mi < 4; ++mi)
      #pragma unroll
      for (int ni = 0; ni < 4; ++ni)
        acc[mi][ni] = __builtin_amdgcn_mfma_f32_16x16x32_bf16(af[mi], bf[ni], acc[mi][ni], 0, 0, 0);
    cur ^= 1;
  }

  const int sec = n0 >> 10;          // uniform per block
  if (sec < 2) {
    short* dst = (sec == 0) ? qb : kb;
    const float qs = (sec == 0) ? 0.125f * LOG2E : 1.0f;
    #pragma unroll
    for (int nA = 0; nA < 2; ++nA) {
      const int colA = n0 + 64 * wn + 16 * nA + lq;
      const float bA = bias[colA], bB = bias[colA + 32];
      const int clA = colA & 1023;
      const int f = 16 * nA + lq;           // 0..31
      #pragma unroll
      for (int mi = 0; mi < 4; ++mi) {
        const int rbase = m0 + 64 * wm + 16 * mi + 4 * g;
        #pragma unroll
        for (int r = 0; r < 4; ++r) {
          const int row = rbase + r, t = row & (T_ - 1);
          const float2 c_s = cs[t * 32 + f];
          const float x1 = acc[mi][nA][r] + bA;
          const float x2 = acc[mi][nA + 2][r] + bB;
          dst[(size_t)row * D_ + clA]      = f2bf((x1 * c_s.x - x2 * c_s.y) * qs);
          dst[(size_t)row * D_ + clA + 32] = f2bf((x2 * c_s.x + x1 * c_s.y) * qs);
        }
      }
    }
  } else {
    #pragma unroll
    for (int ni = 0; ni < 4; ++ni) {
      const int col = n0 + 64 * wn + 16 * ni + lq;
      const float bb = bias[col];
      const int cl = col & 1023;
      const int hh = cl >> 6, d = cl & 63;
      #pragma unroll
      for (int mi = 0; mi < 4; ++mi) {
        const int rbase = m0 + 64 * wm + 16 * mi + 4 * g;
        #pragma unroll
        for (int r = 0; r < 4; ++r) {
          const int row = rbase + r;
          const int bI = row >> 11, t = row & (T_ - 1);
          vt[((size_t)(bI * H_ + hh) * DK_ + d) * T_ + t] = f2bf(acc[mi][ni][r] + bb);
        }
      }
    }
  }
}

// ---------------------------------------------------------------------------
// bf16 MFMA GEMM + bias, fp32 out (out-projection), async dbuf staging.
// ---------------------------------------------------------------------------
__global__ __launch_bounds__(256) void gemm_bf16(const short* __restrict__ A,
                                                 const short* __restrict__ BT,
                                                 const float* __restrict__ bias,
                                                 float* __restrict__ C,
                                                 int M, int N) {
  __shared__ __align__(16) short As[2][GBM][GBK];
  __shared__ __align__(16) short Bs[2][GBN][GBK];
  const int tid = threadIdx.x;
  const int l = tid & 63, g = l >> 4, lq = l & 15;
  const int wm = (tid >> 6) >> 1, wn = (tid >> 6) & 1;
  const int m0 = blockIdx.y * GBM, n0 = blockIdx.x * GBN;

  f32x4 acc[4][4] = {};

  gstage(A, BT, &As[0][0][0], &Bs[0][0][0], tid, (size_t)m0 * D_, (size_t)n0 * D_);
  int cur = 0;
  for (int k0 = 0; k0 < D_; k0 += GBK) {
    __syncthreads();
    if (k0 + GBK < D_)
      gstage(A, BT, &As[cur ^ 1][0][0], &Bs[cur ^ 1][0][0], tid,
             (size_t)m0 * D_ + k0 + GBK, (size_t)n0 * D_ + k0 + GBK);
    sv8 af[4], bf[4];
    #pragma unroll
    for (int mi = 0; mi < 4; ++mi) af[mi] = *(const sv8*)&As[cur][64 * wm + 16 * mi + lq][8 * g];
    #pragma unroll
    for (int ni = 0; ni < 4; ++ni) bf[ni] = *(const sv8*)&Bs[cur][64 * wn + 16 * ni + lq][8 * g];
    #pragma unroll
    for (int mi = 0; mi < 4; ++mi)
      #pragma unroll
      for (int ni = 0; ni < 4; ++ni)
        acc[mi][ni] = __builtin_amdgcn_mfma_f32_16x16x32_bf16(af[mi], bf[ni], acc[mi][ni], 0, 0, 0);
    cur ^= 1;
  }

  #pragma unroll
  for (int ni = 0; ni < 4; ++ni) {
    const int col = n0 + 64 * wn + 16 * ni + lq;
    const float bb = bias[col];
    #pragma unroll
    for (int mi = 0; mi < 4; ++mi) {
      const int rbase = m0 + 64 * wm + 16 * mi + 4 * g;
      #pragma unroll
      for (int r = 0; r < 4; ++r)
        C[(size_t)(rbase + r) * N + col] = acc[mi][ni][r] + bb;
    }
  }
}

// ---------------------------------------------------------------------------
// MFMA flash attention v4: R5-proven staging (int4 + ds_write, 72-stride,
// reg prefetch) + exp2-domain softmax + defer-max + cvt_pk P-pack +
// XCD-aware 1-D grid: wg -> pair=(wg&63) [hh=pair&15, b=pair>>4], bx=wg>>6,
// so all 32 q-blocks of one (b,h) land on one XCD -> K/V L2-resident.
// ---------------------------------------------------------------------------
__global__ __launch_bounds__(256) void flash_mfma(const short* __restrict__ qb,
                                                  const short* __restrict__ kb,
                                                  const short* __restrict__ vt,
                                                  short* __restrict__ out) {
  __shared__ __align__(16) short Ks[64][72];
  __shared__ __align__(16) short Vt[64][72];
  __shared__ __align__(16) short Ps[4][16][72];

  const int tid = threadIdx.x;
  const int w = tid >> 6, l = tid & 63, g = l >> 4, lq = l & 15;
  const int wg = blockIdx.x;
  const int pair = wg & 63, bx = wg >> 6;
  const int hh = pair & 15, b = pair >> 4;
  const int q0 = bx * 64;
  const int qrow = q0 + 16 * w + lq;

  const short* qp = qb + (size_t)(b * T_ + qrow) * D_ + hh * DK_;
  sv8 qf[2];
  qf[0] = *(const sv8*)(qp + 8 * g);
  qf[1] = *(const sv8*)(qp + 32 + 8 * g);

  f32x4 o[4] = {{0,0,0,0},{0,0,0,0},{0,0,0,0},{0,0,0,0}};
  float m_run = -INFINITY, l_run = 0.0f;

  const short* kbB = kb + (size_t)(b * T_) * D_ + hh * DK_;
  const short* vtB = vt + (size_t)(b * H_ + hh) * DK_ * T_;
  const int niter = bx + 1;

  const int skey = tid >> 3, sj = tid & 7;   // staging: key/d row, 8-short chunk

  int4 kr0, kr1, vr0, vr1;
  {
    kr0 = *(const int4*)(kbB + (size_t)(skey)      * D_ + sj * 8);
    kr1 = *(const int4*)(kbB + (size_t)(skey + 32) * D_ + sj * 8);
    vr0 = *(const int4*)(vtB + (size_t)(skey)      * T_ + sj * 8);
    vr1 = *(const int4*)(vtB + (size_t)(skey + 32) * T_ + sj * 8);
  }

  for (int it = 0; it < niter; ++it) {
    const int kv0 = it * 64;
    __syncthreads();
    *(int4*)&Ks[skey][sj * 8]      = kr0;
    *(int4*)&Ks[skey + 32][sj * 8] = kr1;
    *(int4*)&Vt[skey][sj * 8]      = vr0;
    *(int4*)&Vt[skey + 32][sj * 8] = vr1;
    __syncthreads();

    if (it + 1 < niter) {
      const int nk = kv0 + 64;
      kr0 = *(const int4*)(kbB + (size_t)(nk + skey)      * D_ + sj * 8);
      kr1 = *(const int4*)(kbB + (size_t)(nk + skey + 32) * D_ + sj * 8);
      vr0 = *(const int4*)(vtB + (size_t)(skey)      * T_ + nk + sj * 8);
      vr1 = *(const int4*)(vtB + (size_t)(skey + 32) * T_ + nk + sj * 8);
    }

    // --- QK^T (swapped): lane holds q=lq, keys kt*16+4g+r, exp2 domain ---
    float sv[4][4];
    #pragma unroll
    for (int kt = 0; kt < 4; ++kt) {
      f32x4 acc = {0, 0, 0, 0};
      #pragma unroll
      for (int s = 0; s < 2; ++s) {
        const sv8 kf = *(const sv8*)&Ks[kt * 16 + lq][32 * s + 8 * g];
        acc = __builtin_amdgcn_mfma_f32_16x16x32_bf16(kf, qf[s], acc, 0, 0, 0);
      }
      sv[kt][0] = acc[0]; sv[kt][1] = acc[1]; sv[kt][2] = acc[2]; sv[kt][3] = acc[3];
    }

    if (it == niter - 1) {                 // diagonal tile: causal mask
      #pragma unroll
      for (int kt = 0; kt < 4; ++kt)
        #pragma unroll
        for (int r = 0; r < 4; ++r) {
          const int key_abs = kv0 + kt * 16 + 4 * g + r;
          if (key_abs > qrow) sv[kt][r] = -INFINITY;
        }
    }

    // --- online softmax (exp2 domain, defer-max THR=8) ---
    float tm = -INFINITY;
    #pragma unroll
    for (int kt = 0; kt < 4; ++kt)
      #pragma unroll
      for (int r = 0; r < 4; ++r) tm = fmaxf(tm, sv[kt][r]);
    tm = fmaxf(tm, __shfl_xor(tm, 16));
    tm = fmaxf(tm, __shfl_xor(tm, 32));
    if (__any(tm > m_run + 8.0f)) {
      const float mn = fmaxf(m_run, tm);
      const float alpha = __builtin_amdgcn_exp2f(m_run - mn);
      l_run *= alpha;
      #pragma unroll
      for (int r = 0; r < 4; ++r) {
        const float ar = __shfl(alpha, 4 * g + r);
        o[0][r] *= ar; o[1][r] *= ar; o[2][r] *= ar; o[3][r] *= ar;
      }
      m_run = mn;
    }
    float psum = 0.0f;
    #pragma unroll
    for (int kt = 0; kt < 4; ++kt)
      #pragma unroll
      for (int r = 0; r < 4; ++r) {
        const float p = __builtin_amdgcn_exp2f(sv[kt][r] - m_run);
        sv[kt][r] = p;
        psum += p;
      }
    psum += __shfl_xor(psum, 16);
    psum += __shfl_xor(psum, 32);
    l_run += psum;

    // --- pack P to bf16 via cvt_pk ---
    #pragma unroll
    for (int kt = 0; kt < 4; ++kt) {
      unsigned pa_, pb_;
      asm("v_cvt_pk_bf16_f32 %0, %1, %2" : "=v"(pa_) : "v"(sv[kt][0]), "v"(sv[kt][1]));
      asm("v_cvt_pk_bf16_f32 %0, %1, %2" : "=v"(pb_) : "v"(sv[kt][2]), "v"(sv[kt][3]));
      int2 pk; pk.x = (int)pa_; pk.y = (int)pb_;
      *(int2*)&Ps[w][lq][kt * 16 + 4 * g] = pk;
    }

    // --- PV ---
    #pragma unroll
    for (int s = 0; s < 2; ++s) {
      const sv8 pa = *(const sv8*)&Ps[w][lq][32 * s + 8 * g];
      #pragma unroll
      for (int dt = 0; dt < 4; ++dt) {
        const sv8 vb = *(const sv8*)&Vt[dt * 16 + lq][32 * s + 8 * g];
        o[dt] = __builtin_amdgcn_mfma_f32_16x16x32_bf16(pa, vb, o[dt], 0, 0, 0);
      }
    }
  }

  // --- epilogue ---
  #pragma unroll
  for (int r = 0; r < 4; ++r) {
    const float li = __shfl(l_run, 4 * g + r);
    const float inv = 1.0f / li;
    const int qr = q0 + 16 * w + 4 * g + r;
    short* op = out + (size_t)(b * T_ + qr) * D_ + hh * DK_;
    #pragma unroll
    for (int dt = 0; dt < 4; ++dt)
      op[dt * 16 + lq] = f2bf(o[dt][r] * inv);
  }
}

// ---------------------------------------------------------------------------
// launch
// ---------------------------------------------------------------------------
extern "C" void kernel_launch(void* const* d_in, const int* in_sizes, int n_in,
                              void* d_out, int out_size, void* d_ws, size_t ws_size,
                              hipStream_t stream) {
  const float* x     = (const float*)d_in[0];
  const float* ln_w  = (const float*)d_in[1];
  const float* ln_b  = (const float*)d_in[2];
  const float* w_qkv = (const float*)d_in[3];
  const float* b_qkv = (const float*)d_in[4];
  const float* w_o   = (const float*)d_in[5];
  const float* b_o   = (const float*)d_in[6];
  float* outp = (float*)d_out;

  const int rows = B_ * T_;               // 8192
  const size_t nHD = (size_t)rows * D_;   // 8.4M elems

  short* h      = (short*)d_ws;
  short* qb     = h + nHD;
  short* kb     = qb + nHD;
  short* vt     = kb + nHD;
  short* att    = vt + nHD;
  short* wqkvT  = att + nHD;
  short* woT    = wqkvT + (size_t)D_ * 3 * D_;
  float2* csT   = (float2*)(woT + (size_t)D_ * D_);

  rope_tab<<<T_ * 32 / 256, 256, 0, stream>>>(csT);
  conv_t<<<dim3(3 * D_ / 32, D_ / 32), 256, 0, stream>>>(w_qkv, wqkvT, D_, 3 * D_);
  conv_t<<<dim3(D_ / 32, D_ / 32), 256, 0, stream>>>(w_o, woT, D_, D_);

  ln_kernel<<<rows, 256, 0, stream>>>(x, ln_w, ln_b, h);

  {
    dim3 grid(3 * D_ / GBN, rows / GBM);   // (24, 64)
    gemm_qkv_rope<<<grid, 256, 0, stream>>>(h, wqkvT, b_qkv, csT, qb, kb, vt);
  }

  {
    // 1-D grid, XCD-aware: wg -> (pair, bx)
    flash_mfma<<<(T_ / 64) * H_ * B_, 256, 0, stream>>>(qb, kb, vt, att);
  }

  {
    dim3 grid(D_ / GBN, rows / GBM);       // (8, 64)
    gemm_bf16<<<grid, 256, 0, stream>>>(att, woT, b_o, outp, rows, D_);
  }
}